// Round 12
// baseline (303.346 us; speedup 1.0000x reference)
//
#include <hip/hip_runtime.h>

// HierarchicalGraphSAGE bf16-MFMA version, R12.
// N=50000, E=800000, D=128, OUT=64, G=64.
//
//  R12 vs R11: k_sage restructured to barrier-free pure dataflow.
//  R11 still showed k_sage=54us with all pipes idle: the stage->drain->
//  barrier->K-loop phase chain at ~8 waves/CU is a raw latency chain.
//  Fix: ALL GEMM operands now live in MFMA-fragment-packed order
//  ([nb16][s][lane][8], 1KB per (nodeblk,s) fragment):
//   - k_agg writes agg fragments directly (its writes were stores anyway)
//   - k_sage epilogue writes bf16 h fragment-packed (only consumer is the
//     next layer's k_sage; gather uses row-major fp8; pool reads registers)
//   - k_cast_all packs x the same way.
//  k_sage: 32 A-loads + 32 W-loads per wave, every one a coalesced 1KB wave
//  load, 128 MFMAs, no LDS tile, no barrier. Math bit-identical.

typedef __bf16 bf16x8 __attribute__((ext_vector_type(8)));
typedef float f32x4 __attribute__((ext_vector_type(4)));
typedef float f32x2 __attribute__((ext_vector_type(2)));

#define BINB 160          // binning blocks
#define NBMAX 512         // max buckets (N <= 65536)

static __device__ __forceinline__ float bf2f(unsigned short u) {
    union { unsigned u; float f; } c; c.u = (unsigned)u << 16; return c.f;
}
static __device__ __forceinline__ unsigned short f2bf(float f) {
    unsigned u = __builtin_bit_cast(unsigned, f);
    return (unsigned short)((u + 0x7fffu + ((u >> 16) & 1u)) >> 16);
}
static __device__ __forceinline__ uint2 pk8_fp8(const float* f) {
    int lo = 0, hi = 0;
    lo = __builtin_amdgcn_cvt_pk_fp8_f32(f[0], f[1], lo, false);
    lo = __builtin_amdgcn_cvt_pk_fp8_f32(f[2], f[3], lo, true);
    hi = __builtin_amdgcn_cvt_pk_fp8_f32(f[4], f[5], hi, false);
    hi = __builtin_amdgcn_cvt_pk_fp8_f32(f[6], f[7], hi, true);
    return make_uint2((unsigned)lo, (unsigned)hi);
}
static __device__ __forceinline__ unsigned char f2fp8(float v) {
    return (unsigned char)(__builtin_amdgcn_cvt_pk_fp8_f32(v, v, 0, false) & 0xff);
}

// ---------------- bucket counting sort ----------------
__global__ __launch_bounds__(256) void k_bincount(
    const int* __restrict__ dst, int* __restrict__ cnt_mat, int E, int nb, int epb)
{
    __shared__ int lc[NBMAX];
    for (int i = threadIdx.x; i < nb; i += 256) lc[i] = 0;
    __syncthreads();
    int b0 = blockIdx.x * epb;
    int b1 = min(b0 + epb, E);
    for (int i = b0 + threadIdx.x; i < b1; i += 256)
        atomicAdd(&lc[dst[i] >> 7], 1);
    __syncthreads();
    for (int i = threadIdx.x; i < nb; i += 256)
        cnt_mat[i * BINB + blockIdx.x] = lc[i];
}

__global__ __launch_bounds__(256) void k_mrowscan(
    const int* __restrict__ cnt_mat, int* __restrict__ rowloc, int* __restrict__ btot)
{
    __shared__ int s[256];
    int b = blockIdx.x;
    int t = threadIdx.x;
    int v = (t < BINB) ? cnt_mat[b * BINB + t] : 0;
    s[t] = v;
    __syncthreads();
#pragma unroll
    for (int off = 1; off < 256; off <<= 1) {
        int u = (t >= off) ? s[t - off] : 0;
        __syncthreads();
        s[t] += u;
        __syncthreads();
    }
    if (t < BINB) rowloc[b * BINB + t] = s[t] - v;
    if (t == 255) btot[b] = s[255];
}

__global__ __launch_bounds__(256) void k_scan2b(
    const int* __restrict__ btot, int* __restrict__ bbase, int nb, int* __restrict__ total_out)
{
    __shared__ int s[256];
    int t = threadIdx.x;
    int per = (nb + 255) / 256;
    int s0 = t * per, e0 = min(s0 + per, nb);
    int sum = 0;
    for (int i = s0; i < e0; ++i) sum += btot[i];
    s[t] = sum;
    __syncthreads();
#pragma unroll
    for (int off = 1; off < 256; off <<= 1) {
        int u = (t >= off) ? s[t - off] : 0;
        __syncthreads();
        s[t] += u;
        __syncthreads();
    }
    int run = s[t] - sum;
    for (int i = s0; i < e0; ++i) { bbase[i] = run; run += btot[i]; }
    if (t == 255) *total_out = s[255];
}

__global__ __launch_bounds__(256) void k_binscatter(
    const int* __restrict__ ei, const int* __restrict__ rowloc, const int* __restrict__ bbase,
    unsigned* __restrict__ binned, int E, int nb, int epb)
{
    __shared__ int lofs[NBMAX];
    __shared__ int lcnt[NBMAX];
    for (int i = threadIdx.x; i < nb; i += 256) {
        lofs[i] = rowloc[i * BINB + blockIdx.x] + bbase[i];
        lcnt[i] = 0;
    }
    __syncthreads();
    int b0 = blockIdx.x * epb;
    int b1 = min(b0 + epb, E);
    for (int i = b0 + threadIdx.x; i < b1; i += 256) {
        int s = ei[i];
        int d = ei[E + i];
        int b = d >> 7;
        int r = atomicAdd(&lcnt[b], 1);
        binned[lofs[b] + r] = (unsigned)s | ((unsigned)(d & 127) << 16);
    }
}

__global__ __launch_bounds__(256) void k_fillfine2(
    const unsigned* __restrict__ binned, const int* __restrict__ bbase,
    int* __restrict__ starts, unsigned short* __restrict__ csr_src,
    int E, int nb, int n)
{
    __shared__ int lc[128];
    __shared__ int lpos[128];
    int b = blockIdx.x;
    int t = threadIdx.x;
    int node0 = b << 7;
    int bs = bbase[b];
    int be = (b == nb - 1) ? E : bbase[b + 1];
    if (t < 128) lc[t] = 0;
    __syncthreads();
    for (int i = bs + t; i < be; i += 256)
        atomicAdd(&lc[(binned[i] >> 16) & 127], 1);
    __syncthreads();
    int v = (t < 128) ? lc[t] : 0;
    if (t < 128) lpos[t] = v;
    __syncthreads();
#pragma unroll
    for (int off = 1; off < 128; off <<= 1) {
        int u = (t >= off && t < 128) ? lpos[t - off] : 0;
        __syncthreads();
        if (t < 128) lpos[t] += u;
        __syncthreads();
    }
    int excl = (t < 128) ? (lpos[t] - v) : 0;
    __syncthreads();
    if (t < 128) {
        int node = node0 + t;
        if (node < n) starts[node] = bs + excl;
        lpos[t] = bs + excl;
    }
    if (b == nb - 1 && t == 0) starts[n] = E;
    __syncthreads();
    for (int i = bs + t; i < be; i += 256) {
        unsigned e = binned[i];
        int slot = atomicAdd(&lpos[(e >> 16) & 127], 1);
        csr_src[slot] = (unsigned short)(e & 0xffffu);
    }
}

// ---------------- casts: x -> bf16-fragments + fp8-rows; W -> frag pack ----
// Fragment layout (per 16-node block, K=128): addr = nb*2048 + s*512 +
// (quad*16 + m)*8 + e, where s=k>>5, quad=(k>>3)&3, e=k&7, m=node&15.
__global__ __launch_bounds__(256) void k_cast_all(
    const float* __restrict__ x, unsigned short* __restrict__ xb,
    unsigned char* __restrict__ x8, int n8, int nxblk,
    const float* __restrict__ W1l, const float* __restrict__ W1r,
    const float* __restrict__ W2l, const float* __restrict__ W2r,
    const float* __restrict__ W3l, const float* __restrict__ W3r,
    unsigned short* __restrict__ Whi, unsigned short* __restrict__ Wlo)
{
    int bid = blockIdx.x;
    if (bid < nxblk) {
        int i = bid * 256 + threadIdx.x;
        if (i >= n8) return;
        float f[8];
        *(float4*)(f + 0) = *(const float4*)(x + (size_t)i * 8);
        *(float4*)(f + 4) = *(const float4*)(x + (size_t)i * 8 + 4);
        ushort4 oa, ob;
        oa.x = f2bf(f[0]); oa.y = f2bf(f[1]); oa.z = f2bf(f[2]); oa.w = f2bf(f[3]);
        ob.x = f2bf(f[4]); ob.y = f2bf(f[5]); ob.z = f2bf(f[6]); ob.w = f2bf(f[7]);
        int node = i >> 4, c = i & 15;  // chunk c = 8 elems at k=c*8
        size_t dst = (size_t)(node >> 4) * 2048 + (size_t)(c >> 2) * 512
                   + (size_t)((c & 3) * 16 + (node & 15)) * 8;
        *(ushort4*)(xb + dst) = oa;
        *(ushort4*)(xb + dst + 4) = ob;
        *(uint2*)(x8 + (size_t)i * 8) = pk8_fp8(f);   // row-major fp8
    } else {
        int wb = bid - nxblk;          // 0..383
        int layer = wb >> 7;
        int j = wb & 127;
        int k = threadIdx.x;           // 0..255
        const float* Wl = (layer == 0) ? W1l : (layer == 1) ? W2l : W3l;
        const float* Wr = (layer == 0) ? W1r : (layer == 1) ? W2r : W3r;
        float w = (k < 128) ? Wl[j * 128 + k] : Wr[j * 128 + k - 128];
        unsigned short hi = f2bf(w);
        float lo = w - bf2f(hi);
        int wv = j >> 5, jj = (j >> 4) & 1, mr = j & 15;
        int s = k >> 5, quad = (k >> 3) & 3, e = k & 7;
        int lane = quad * 16 + mr;
        size_t o = (size_t)layer * 32768
                 + ((size_t)(((wv * 8 + s) * 2 + jj)) * 64 + lane) * 8 + e;
        Whi[o] = hi;
        Wlo[o] = f2bf(lo);
    }
}

// ---------------- aggregate: fp8-row gather -> fragment-packed bf16 agg ----
__global__ __launch_bounds__(256) void k_agg(
    const unsigned char* __restrict__ h8, const int* __restrict__ starts,
    const unsigned short* __restrict__ csr, unsigned short* __restrict__ aggf, int n)
{
    int node = blockIdx.x * 4 + (threadIdx.x >> 6);
    int lane = threadIdx.x & 63;
    if (node >= n) return;
    int eg = lane >> 4;
    int fb = lane & 15;
    const unsigned char* hrow = h8 + fb * 8;
    int s = starts[node], e = starts[node + 1];
    float a0 = 0.f, a1 = 0.f, a2 = 0.f, a3 = 0.f,
          a4 = 0.f, a5 = 0.f, a6 = 0.f, a7 = 0.f;

#define ACC8(v)                                                         \
    do {                                                                \
        f32x2 p0 = __builtin_amdgcn_cvt_pk_f32_fp8((v).x, false);       \
        f32x2 p1 = __builtin_amdgcn_cvt_pk_f32_fp8((v).x, true);        \
        f32x2 p2 = __builtin_amdgcn_cvt_pk_f32_fp8((v).y, false);       \
        f32x2 p3 = __builtin_amdgcn_cvt_pk_f32_fp8((v).y, true);        \
        a0 += p0.x; a1 += p0.y; a2 += p1.x; a3 += p1.y;                 \
        a4 += p2.x; a5 += p2.y; a6 += p3.x; a7 += p3.y;                 \
    } while (0)

    for (int base = s; base < e; base += 64) {
        int cnt = min(64, e - base);
        int idx = (base + lane < e) ? (int)csr[base + lane] : 0;
        int j = 0;
        for (; j + 8 <= cnt; j += 8) {
            int s0 = __shfl(idx, j + eg);
            int s1 = __shfl(idx, j + 4 + eg);
            uint2 v0 = *(const uint2*)(hrow + (size_t)s0 * 128);
            uint2 v1 = *(const uint2*)(hrow + (size_t)s1 * 128);
            ACC8(v0);
            ACC8(v1);
        }
        for (; j + 4 <= cnt; j += 4) {
            int s0 = __shfl(idx, j + eg);
            uint2 v0 = *(const uint2*)(hrow + (size_t)s0 * 128);
            ACC8(v0);
        }
        if (j < cnt) {
            int k = j + eg;
            int sm = __shfl(idx, (k < cnt) ? k : (cnt - 1));
            uint2 v = *(const uint2*)(hrow + (size_t)sm * 128);
            if (k >= cnt) v = make_uint2(0u, 0u);
            ACC8(v);
        }
    }
#undef ACC8

    a0 += __shfl_xor(a0, 16); a0 += __shfl_xor(a0, 32);
    a1 += __shfl_xor(a1, 16); a1 += __shfl_xor(a1, 32);
    a2 += __shfl_xor(a2, 16); a2 += __shfl_xor(a2, 32);
    a3 += __shfl_xor(a3, 16); a3 += __shfl_xor(a3, 32);
    a4 += __shfl_xor(a4, 16); a4 += __shfl_xor(a4, 32);
    a5 += __shfl_xor(a5, 16); a5 += __shfl_xor(a5, 32);
    a6 += __shfl_xor(a6, 16); a6 += __shfl_xor(a6, 32);
    a7 += __shfl_xor(a7, 16); a7 += __shfl_xor(a7, 32);

    unsigned u0 = (unsigned)f2bf(a0) | ((unsigned)f2bf(a1) << 16);
    unsigned u1 = (unsigned)f2bf(a2) | ((unsigned)f2bf(a3) << 16);
    unsigned u2 = (unsigned)f2bf(a4) | ((unsigned)f2bf(a5) << 16);
    unsigned u3 = (unsigned)f2bf(a6) | ((unsigned)f2bf(a7) << 16);
    if (eg == 0) {
        // fragment-packed write: k-chunk fb -> s=fb>>2, quad=fb&3
        size_t dst = (size_t)(node >> 4) * 2048 + (size_t)(fb >> 2) * 512
                   + (size_t)((fb & 3) * 16 + (node & 15)) * 8;
        *(uint4*)(aggf + dst) = make_uint4(u0, u1, u2, u3);
    }
}

// ---------------- SAGE layer GEMM: barrier-free, fragment operands ---------
// Wave wv of 4: j-strip [32wv,32wv+32), 64 nodes (4 nodeblks). All operand
// loads are coalesced 1KB wave loads. No LDS A-tile, no __syncthreads
// (except pool flush in the do_pool layer).
__global__ __launch_bounds__(256) void k_sage(
    const unsigned short* __restrict__ aggf, const unsigned short* __restrict__ hf,
    const unsigned short* __restrict__ Whi, const unsigned short* __restrict__ Wlo,
    const float* __restrict__ bl, unsigned short* __restrict__ outf,
    unsigned char* __restrict__ out8, const int* __restrict__ batch,
    float* __restrict__ gsum, int n, int do_relu, int do_out8, int do_pool)
{
    __shared__ float pool[8][128];           // 4 KB, used only when do_pool
    int node0 = blockIdx.x * 64;
    int nb0 = blockIdx.x * 4;                // nodeblk base
    int t = threadIdx.x;
    int wv = t >> 6;
    int l = t & 63;
    int quad = l >> 4;
    int mr = l & 15;
    int jbase = wv * 32;

    if (do_pool) {
        for (int q = t; q < 1024; q += 256) pool[q >> 7][q & 127] = 0.f;
        __syncthreads();
    }

    f32x4 acc[4][2];
#pragma unroll
    for (int mi = 0; mi < 4; ++mi)
#pragma unroll
        for (int jj = 0; jj < 2; ++jj) acc[mi][jj] = (f32x4){0.f, 0.f, 0.f, 0.f};

    const unsigned short* wphi = Whi + ((size_t)wv * 16) * 512 + (size_t)l * 8;
    const unsigned short* wplo = Wlo + ((size_t)wv * 16) * 512 + (size_t)l * 8;

    for (int s = 0; s < 8; ++s) {
        bf16x8 bh[2], bo[2];
#pragma unroll
        for (int jj = 0; jj < 2; ++jj) {
            size_t fo = (size_t)(s * 2 + jj) * 512;
            bh[jj] = __builtin_bit_cast(bf16x8, *(const uint4*)(wphi + fo));
            bo[jj] = __builtin_bit_cast(bf16x8, *(const uint4*)(wplo + fo));
        }
        const unsigned short* abase = (s < 4)
            ? (aggf + (size_t)s * 512 + (size_t)l * 8)
            : (hf + (size_t)(s - 4) * 512 + (size_t)l * 8);
#pragma unroll
        for (int mi = 0; mi < 4; ++mi) {
            bf16x8 a = __builtin_bit_cast(
                bf16x8, *(const uint4*)(abase + (size_t)(nb0 + mi) * 2048));
#pragma unroll
            for (int jj = 0; jj < 2; ++jj) {
                acc[mi][jj] = __builtin_amdgcn_mfma_f32_16x16x32_bf16(a, bh[jj], acc[mi][jj], 0, 0, 0);
                acc[mi][jj] = __builtin_amdgcn_mfma_f32_16x16x32_bf16(a, bo[jj], acc[mi][jj], 0, 0, 0);
            }
        }
    }

    int g0 = do_pool ? batch[min(node0, n - 1)] : 0;

#pragma unroll
    for (int mi = 0; mi < 4; ++mi) {
#pragma unroll
        for (int jj = 0; jj < 2; ++jj) {
            int col = jbase + jj * 16 + mr;
            float bias = bl[col];
            int q2 = (col >> 3) & 3;
            int e2 = col & 7;
#pragma unroll
            for (int r = 0; r < 4; ++r) {
                int node = node0 + mi * 16 + quad * 4 + r;
                if (node >= n) continue;
                float v = acc[mi][jj][r] + bias;
                if (do_relu) v = fmaxf(v, 0.f);
                // fragment-packed bf16 write (next layer's h operand):
                // s_int = col>>5 = wv
                outf[(size_t)(node >> 4) * 2048 + (size_t)wv * 512
                     + (size_t)(q2 * 16 + (node & 15)) * 8 + e2] = f2bf(v);
                if (do_out8) out8[(size_t)node * 128 + col] = f2fp8(v);
                if (do_pool) {
                    int gi = batch[node] - g0;
                    if (gi < 8) atomicAdd(&pool[gi][col], v);
                    else atomicAdd(&gsum[batch[node] * 128 + col], v);
                }
            }
        }
    }

    if (do_pool) {
        __syncthreads();
        for (int q = t; q < 1024; q += 256) {
            int s = q >> 7, c = q & 127;
            float v = pool[s][c];
            if (v != 0.f && g0 + s < 64)
                atomicAdd(&gsum[(g0 + s) * 128 + c], v);
        }
    }
}

// ---------------- final: mean-pool normalize + linear head -----------------
__global__ void k_final(const float* __restrict__ gsum, const int* __restrict__ batch,
                        const float* __restrict__ Wlin, const float* __restrict__ blin,
                        float* __restrict__ out, int n)
{
    int g = blockIdx.x;   // 64
    int o = threadIdx.x;  // 64
    int lo = 0, hi = n;
    while (lo < hi) { int m = (lo + hi) >> 1; if (batch[m] < g) lo = m + 1; else hi = m; }
    int lb = lo;
    hi = n;
    while (lo < hi) { int m = (lo + hi) >> 1; if (batch[m] < g + 1) lo = m + 1; else hi = m; }
    float cntf = (float)(lo - lb);
    float inv = 1.f / fmaxf(cntf, 1.f);
    float acc = 0.f;
    for (int k = 0; k < 128; ++k)
        acc += gsum[g * 128 + k] * Wlin[o * 128 + k];
    out[g * 64 + o] = acc * inv + blin[o];
}

extern "C" void kernel_launch(void* const* d_in, const int* in_sizes, int n_in,
                              void* d_out, int out_size, void* d_ws, size_t ws_size,
                              hipStream_t stream) {
    const float* x     = (const float*)d_in[0];
    const int*   ei    = (const int*)d_in[1];
    const int*   batch = (const int*)d_in[2];
    const float* W1l = (const float*)d_in[3];
    const float* b1l = (const float*)d_in[4];
    const float* W1r = (const float*)d_in[5];
    const float* W2l = (const float*)d_in[6];
    const float* b2l = (const float*)d_in[7];
    const float* W2r = (const float*)d_in[8];
    const float* W3l = (const float*)d_in[9];
    const float* b3l = (const float*)d_in[10];
    const float* W3r = (const float*)d_in[11];
    const float* Wlin = (const float*)d_in[12];
    const float* blin = (const float*)d_in[13];

    const int N = in_sizes[2];       // 50000
    const int E = in_sizes[1] / 2;   // 800000
    const int nb = (N + 127) >> 7;   // 391 buckets
    const int epb = (E + BINB - 1) / BINB;  // 5000 edges per bin block

    size_t off = 0;
    auto alloc = [&](size_t bytes) {
        void* p = (char*)d_ws + off;
        off += (bytes + 255) & ~(size_t)255;
        return p;
    };
    int* csr_start = (int*)alloc((size_t)(N + 1) * 4);
    int* cnt_mat   = (int*)alloc((size_t)nb * BINB * 4);
    int* rowloc    = (int*)alloc((size_t)nb * BINB * 4);
    int* btot      = (int*)alloc((size_t)NBMAX * 4);
    int* bbase     = (int*)alloc((size_t)NBMAX * 4);
    unsigned short* csr_src = (unsigned short*)alloc((size_t)E * 2);
    unsigned short* x_bf   = (unsigned short*)alloc((size_t)N * 128 * 2 + 65536);
    unsigned short* hA     = (unsigned short*)alloc((size_t)N * 128 * 2 + 65536);
    unsigned short* hB     = (unsigned short*)alloc((size_t)N * 128 * 2 + 65536);
    unsigned short* agg_bf = (unsigned short*)alloc((size_t)N * 128 * 2 + 65536);
    unsigned char*  h_f8   = (unsigned char*)alloc((size_t)N * 128);
    unsigned short* Whi = (unsigned short*)alloc(3 * 128 * 256 * 2);
    unsigned short* Wlo = (unsigned short*)alloc(3 * 128 * 256 * 2);
    float* gsum = (float*)alloc((size_t)64 * 128 * 4);
    (void)ws_size;

    // binned aliases agg_bf: consumed by k_fillfine2 before first k_agg write.
    unsigned* binned = (unsigned*)agg_bf;

    hipMemsetAsync(gsum, 0, (size_t)64 * 128 * 4, stream);

    // --- CSR build (5 launches) ---
    k_bincount<<<BINB, 256, 0, stream>>>(ei + E, cnt_mat, E, nb, epb);
    k_mrowscan<<<nb, 256, 0, stream>>>(cnt_mat, rowloc, btot);
    k_scan2b<<<1, 256, 0, stream>>>(btot, bbase, nb, csr_start + N);
    k_binscatter<<<BINB, 256, 0, stream>>>(ei, rowloc, bbase, binned, E, nb, epb);
    k_fillfine2<<<nb, 256, 0, stream>>>(binned, bbase, csr_start, csr_src, E, nb, N);

    // --- casts (1 launch) ---
    int n8 = N * 128 / 8;             // 800000
    int nxblk = (n8 + 255) / 256;     // 3125
    k_cast_all<<<nxblk + 3 * 128, 256, 0, stream>>>(
        x, x_bf, h_f8, n8, nxblk, W1l, W1r, W2l, W2r, W3l, W3r, Whi, Wlo);

    int agg_grid = (N + 3) / 4;
    int sage_grid = (N + 63) / 64;

    // Layer 1: gather fp8(x) -> agg frags; GEMM -> hA frags (relu) + fp8 rows
    k_agg<<<agg_grid, 256, 0, stream>>>(h_f8, csr_start, csr_src, agg_bf, N);
    k_sage<<<sage_grid, 256, 0, stream>>>(agg_bf, x_bf, Whi, Wlo, b1l,
                                          hA, h_f8, batch, gsum, N, 1, 1, 0);
    // Layer 2
    k_agg<<<agg_grid, 256, 0, stream>>>(h_f8, csr_start, csr_src, agg_bf, N);
    k_sage<<<sage_grid, 256, 0, stream>>>(agg_bf, hA, Whi + 32768, Wlo + 32768, b2l,
                                          hB, h_f8, batch, gsum, N, 1, 1, 0);
    // Layer 3 (no relu, pool fused)
    k_agg<<<agg_grid, 256, 0, stream>>>(h_f8, csr_start, csr_src, agg_bf, N);
    k_sage<<<sage_grid, 256, 0, stream>>>(agg_bf, hB, Whi + 65536, Wlo + 65536, b3l,
                                          hA, h_f8, batch, gsum, N, 0, 0, 1);

    // Head
    k_final<<<64, 64, 0, stream>>>(gsum, batch, Wlin, blin, (float*)d_out, N);
}

// Round 13
// 296.674 us; speedup vs baseline: 1.0225x; 1.0225x over previous
//
#include <hip/hip_runtime.h>

// HierarchicalGraphSAGE bf16-MFMA version, R13.
// N=50000, E=800000, D=128, OUT=64, G=64.
//
//  R13 vs R12: k_sage work reshape for occupancy. R10/R11/R12 all pinned
//  k_sage at ~55us with every pipe idle regardless of structure; common
//  factor was the 782-block grid (12 waves/CU demanded, ~6 resident).
//  Now: wave = 32 nodes x 16 j (was 64x32), grid = 3126 blocks (node-pair
//  x j-half), 12500 waves = 49/CU demanded -> VGPR-capped 32/CU resident.
//  Same 400k MFMAs, same fragment layouts, bit-identical accumulation.

typedef __bf16 bf16x8 __attribute__((ext_vector_type(8)));
typedef float f32x4 __attribute__((ext_vector_type(4)));
typedef float f32x2 __attribute__((ext_vector_type(2)));

#define BINB 160          // binning blocks
#define NBMAX 512         // max buckets (N <= 65536)

static __device__ __forceinline__ float bf2f(unsigned short u) {
    union { unsigned u; float f; } c; c.u = (unsigned)u << 16; return c.f;
}
static __device__ __forceinline__ unsigned short f2bf(float f) {
    unsigned u = __builtin_bit_cast(unsigned, f);
    return (unsigned short)((u + 0x7fffu + ((u >> 16) & 1u)) >> 16);
}
static __device__ __forceinline__ uint2 pk8_fp8(const float* f) {
    int lo = 0, hi = 0;
    lo = __builtin_amdgcn_cvt_pk_fp8_f32(f[0], f[1], lo, false);
    lo = __builtin_amdgcn_cvt_pk_fp8_f32(f[2], f[3], lo, true);
    hi = __builtin_amdgcn_cvt_pk_fp8_f32(f[4], f[5], hi, false);
    hi = __builtin_amdgcn_cvt_pk_fp8_f32(f[6], f[7], hi, true);
    return make_uint2((unsigned)lo, (unsigned)hi);
}
static __device__ __forceinline__ unsigned char f2fp8(float v) {
    return (unsigned char)(__builtin_amdgcn_cvt_pk_fp8_f32(v, v, 0, false) & 0xff);
}

// ---------------- bucket counting sort ----------------
__global__ __launch_bounds__(256) void k_bincount(
    const int* __restrict__ dst, int* __restrict__ cnt_mat, int E, int nb, int epb)
{
    __shared__ int lc[NBMAX];
    for (int i = threadIdx.x; i < nb; i += 256) lc[i] = 0;
    __syncthreads();
    int b0 = blockIdx.x * epb;
    int b1 = min(b0 + epb, E);
    for (int i = b0 + threadIdx.x; i < b1; i += 256)
        atomicAdd(&lc[dst[i] >> 7], 1);
    __syncthreads();
    for (int i = threadIdx.x; i < nb; i += 256)
        cnt_mat[i * BINB + blockIdx.x] = lc[i];
}

__global__ __launch_bounds__(256) void k_mrowscan(
    const int* __restrict__ cnt_mat, int* __restrict__ rowloc, int* __restrict__ btot)
{
    __shared__ int s[256];
    int b = blockIdx.x;
    int t = threadIdx.x;
    int v = (t < BINB) ? cnt_mat[b * BINB + t] : 0;
    s[t] = v;
    __syncthreads();
#pragma unroll
    for (int off = 1; off < 256; off <<= 1) {
        int u = (t >= off) ? s[t - off] : 0;
        __syncthreads();
        s[t] += u;
        __syncthreads();
    }
    if (t < BINB) rowloc[b * BINB + t] = s[t] - v;
    if (t == 255) btot[b] = s[255];
}

__global__ __launch_bounds__(256) void k_scan2b(
    const int* __restrict__ btot, int* __restrict__ bbase, int nb, int* __restrict__ total_out)
{
    __shared__ int s[256];
    int t = threadIdx.x;
    int per = (nb + 255) / 256;
    int s0 = t * per, e0 = min(s0 + per, nb);
    int sum = 0;
    for (int i = s0; i < e0; ++i) sum += btot[i];
    s[t] = sum;
    __syncthreads();
#pragma unroll
    for (int off = 1; off < 256; off <<= 1) {
        int u = (t >= off) ? s[t - off] : 0;
        __syncthreads();
        s[t] += u;
        __syncthreads();
    }
    int run = s[t] - sum;
    for (int i = s0; i < e0; ++i) { bbase[i] = run; run += btot[i]; }
    if (t == 255) *total_out = s[255];
}

__global__ __launch_bounds__(256) void k_binscatter(
    const int* __restrict__ ei, const int* __restrict__ rowloc, const int* __restrict__ bbase,
    unsigned* __restrict__ binned, int E, int nb, int epb)
{
    __shared__ int lofs[NBMAX];
    __shared__ int lcnt[NBMAX];
    for (int i = threadIdx.x; i < nb; i += 256) {
        lofs[i] = rowloc[i * BINB + blockIdx.x] + bbase[i];
        lcnt[i] = 0;
    }
    __syncthreads();
    int b0 = blockIdx.x * epb;
    int b1 = min(b0 + epb, E);
    for (int i = b0 + threadIdx.x; i < b1; i += 256) {
        int s = ei[i];
        int d = ei[E + i];
        int b = d >> 7;
        int r = atomicAdd(&lcnt[b], 1);
        binned[lofs[b] + r] = (unsigned)s | ((unsigned)(d & 127) << 16);
    }
}

__global__ __launch_bounds__(256) void k_fillfine2(
    const unsigned* __restrict__ binned, const int* __restrict__ bbase,
    int* __restrict__ starts, unsigned short* __restrict__ csr_src,
    int E, int nb, int n)
{
    __shared__ int lc[128];
    __shared__ int lpos[128];
    int b = blockIdx.x;
    int t = threadIdx.x;
    int node0 = b << 7;
    int bs = bbase[b];
    int be = (b == nb - 1) ? E : bbase[b + 1];
    if (t < 128) lc[t] = 0;
    __syncthreads();
    for (int i = bs + t; i < be; i += 256)
        atomicAdd(&lc[(binned[i] >> 16) & 127], 1);
    __syncthreads();
    int v = (t < 128) ? lc[t] : 0;
    if (t < 128) lpos[t] = v;
    __syncthreads();
#pragma unroll
    for (int off = 1; off < 128; off <<= 1) {
        int u = (t >= off && t < 128) ? lpos[t - off] : 0;
        __syncthreads();
        if (t < 128) lpos[t] += u;
        __syncthreads();
    }
    int excl = (t < 128) ? (lpos[t] - v) : 0;
    __syncthreads();
    if (t < 128) {
        int node = node0 + t;
        if (node < n) starts[node] = bs + excl;
        lpos[t] = bs + excl;
    }
    if (b == nb - 1 && t == 0) starts[n] = E;
    __syncthreads();
    for (int i = bs + t; i < be; i += 256) {
        unsigned e = binned[i];
        int slot = atomicAdd(&lpos[(e >> 16) & 127], 1);
        csr_src[slot] = (unsigned short)(e & 0xffffu);
    }
}

// ---------------- casts: x -> bf16-fragments + fp8-rows; W -> frag pack ----
__global__ __launch_bounds__(256) void k_cast_all(
    const float* __restrict__ x, unsigned short* __restrict__ xb,
    unsigned char* __restrict__ x8, int n8, int nxblk,
    const float* __restrict__ W1l, const float* __restrict__ W1r,
    const float* __restrict__ W2l, const float* __restrict__ W2r,
    const float* __restrict__ W3l, const float* __restrict__ W3r,
    unsigned short* __restrict__ Whi, unsigned short* __restrict__ Wlo)
{
    int bid = blockIdx.x;
    if (bid < nxblk) {
        int i = bid * 256 + threadIdx.x;
        if (i >= n8) return;
        float f[8];
        *(float4*)(f + 0) = *(const float4*)(x + (size_t)i * 8);
        *(float4*)(f + 4) = *(const float4*)(x + (size_t)i * 8 + 4);
        ushort4 oa, ob;
        oa.x = f2bf(f[0]); oa.y = f2bf(f[1]); oa.z = f2bf(f[2]); oa.w = f2bf(f[3]);
        ob.x = f2bf(f[4]); ob.y = f2bf(f[5]); ob.z = f2bf(f[6]); ob.w = f2bf(f[7]);
        int node = i >> 4, c = i & 15;
        size_t dst = (size_t)(node >> 4) * 2048 + (size_t)(c >> 2) * 512
                   + (size_t)((c & 3) * 16 + (node & 15)) * 8;
        *(ushort4*)(xb + dst) = oa;
        *(ushort4*)(xb + dst + 4) = ob;
        *(uint2*)(x8 + (size_t)i * 8) = pk8_fp8(f);
    } else {
        int wb = bid - nxblk;
        int layer = wb >> 7;
        int j = wb & 127;
        int k = threadIdx.x;
        const float* Wl = (layer == 0) ? W1l : (layer == 1) ? W2l : W3l;
        const float* Wr = (layer == 0) ? W1r : (layer == 1) ? W2r : W3r;
        float w = (k < 128) ? Wl[j * 128 + k] : Wr[j * 128 + k - 128];
        unsigned short hi = f2bf(w);
        float lo = w - bf2f(hi);
        int wv = j >> 5, jj = (j >> 4) & 1, mr = j & 15;
        int s = k >> 5, quad = (k >> 3) & 3, e = k & 7;
        int lane = quad * 16 + mr;
        size_t o = (size_t)layer * 32768
                 + ((size_t)(((wv * 8 + s) * 2 + jj)) * 64 + lane) * 8 + e;
        Whi[o] = hi;
        Wlo[o] = f2bf(lo);
    }
}

// ---------------- aggregate: fp8-row gather -> fragment-packed bf16 agg ----
__global__ __launch_bounds__(256) void k_agg(
    const unsigned char* __restrict__ h8, const int* __restrict__ starts,
    const unsigned short* __restrict__ csr, unsigned short* __restrict__ aggf, int n)
{
    int node = blockIdx.x * 4 + (threadIdx.x >> 6);
    int lane = threadIdx.x & 63;
    if (node >= n) return;
    int eg = lane >> 4;
    int fb = lane & 15;
    const unsigned char* hrow = h8 + fb * 8;
    int s = starts[node], e = starts[node + 1];
    float a0 = 0.f, a1 = 0.f, a2 = 0.f, a3 = 0.f,
          a4 = 0.f, a5 = 0.f, a6 = 0.f, a7 = 0.f;

#define ACC8(v)                                                         \
    do {                                                                \
        f32x2 p0 = __builtin_amdgcn_cvt_pk_f32_fp8((v).x, false);       \
        f32x2 p1 = __builtin_amdgcn_cvt_pk_f32_fp8((v).x, true);        \
        f32x2 p2 = __builtin_amdgcn_cvt_pk_f32_fp8((v).y, false);       \
        f32x2 p3 = __builtin_amdgcn_cvt_pk_f32_fp8((v).y, true);        \
        a0 += p0.x; a1 += p0.y; a2 += p1.x; a3 += p1.y;                 \
        a4 += p2.x; a5 += p2.y; a6 += p3.x; a7 += p3.y;                 \
    } while (0)

    for (int base = s; base < e; base += 64) {
        int cnt = min(64, e - base);
        int idx = (base + lane < e) ? (int)csr[base + lane] : 0;
        int j = 0;
        for (; j + 8 <= cnt; j += 8) {
            int s0 = __shfl(idx, j + eg);
            int s1 = __shfl(idx, j + 4 + eg);
            uint2 v0 = *(const uint2*)(hrow + (size_t)s0 * 128);
            uint2 v1 = *(const uint2*)(hrow + (size_t)s1 * 128);
            ACC8(v0);
            ACC8(v1);
        }
        for (; j + 4 <= cnt; j += 4) {
            int s0 = __shfl(idx, j + eg);
            uint2 v0 = *(const uint2*)(hrow + (size_t)s0 * 128);
            ACC8(v0);
        }
        if (j < cnt) {
            int k = j + eg;
            int sm = __shfl(idx, (k < cnt) ? k : (cnt - 1));
            uint2 v = *(const uint2*)(hrow + (size_t)sm * 128);
            if (k >= cnt) v = make_uint2(0u, 0u);
            ACC8(v);
        }
    }
#undef ACC8

    a0 += __shfl_xor(a0, 16); a0 += __shfl_xor(a0, 32);
    a1 += __shfl_xor(a1, 16); a1 += __shfl_xor(a1, 32);
    a2 += __shfl_xor(a2, 16); a2 += __shfl_xor(a2, 32);
    a3 += __shfl_xor(a3, 16); a3 += __shfl_xor(a3, 32);
    a4 += __shfl_xor(a4, 16); a4 += __shfl_xor(a4, 32);
    a5 += __shfl_xor(a5, 16); a5 += __shfl_xor(a5, 32);
    a6 += __shfl_xor(a6, 16); a6 += __shfl_xor(a6, 32);
    a7 += __shfl_xor(a7, 16); a7 += __shfl_xor(a7, 32);

    unsigned u0 = (unsigned)f2bf(a0) | ((unsigned)f2bf(a1) << 16);
    unsigned u1 = (unsigned)f2bf(a2) | ((unsigned)f2bf(a3) << 16);
    unsigned u2 = (unsigned)f2bf(a4) | ((unsigned)f2bf(a5) << 16);
    unsigned u3 = (unsigned)f2bf(a6) | ((unsigned)f2bf(a7) << 16);
    if (eg == 0) {
        size_t dst = (size_t)(node >> 4) * 2048 + (size_t)(fb >> 2) * 512
                   + (size_t)((fb & 3) * 16 + (node & 15)) * 8;
        *(uint4*)(aggf + dst) = make_uint4(u0, u1, u2, u3);
    }
}

// ---------------- SAGE layer GEMM: 32 nodes x 16 j per wave ----------------
// Grid: blockIdx.x = pair*2 + jhalf. Wave wv: j-strip js = jhalf*4+wv
// (16 j), node pair = 2 nodeblks. Per s: 2 W loads + 2 A loads, 4 MFMAs.
// All loads coalesced 1KB wave loads; no LDS tile, no barrier (except pool).
__global__ __launch_bounds__(256) void k_sage(
    const unsigned short* __restrict__ aggf, const unsigned short* __restrict__ hf,
    const unsigned short* __restrict__ Whi, const unsigned short* __restrict__ Wlo,
    const float* __restrict__ bl, unsigned short* __restrict__ outf,
    unsigned char* __restrict__ out8, const int* __restrict__ batch,
    float* __restrict__ gsum, int n, int do_relu, int do_out8, int do_pool)
{
    __shared__ float pool[8][128];
    int bid = blockIdx.x;
    int pair = bid >> 1;
    int jh = bid & 1;
    int t = threadIdx.x;
    int wv = t >> 6;
    int l = t & 63;
    int quad = l >> 4;
    int mr = l & 15;
    int js = jh * 4 + wv;         // j-strip 0..7
    int jbase = js * 16;
    int nb0 = pair * 2;
    int node0 = pair * 32;

    if (do_pool) {
        for (int q = t; q < 1024; q += 256) pool[q >> 7][q & 127] = 0.f;
        __syncthreads();
    }

    f32x4 acc0 = (f32x4){0.f, 0.f, 0.f, 0.f};
    f32x4 acc1 = (f32x4){0.f, 0.f, 0.f, 0.f};

    // frag index for (js, s): ((js>>1)*8 + s)*2 + (js&1)
    const unsigned short* wphi = Whi + (size_t)(js >> 1) * 8192
                               + (size_t)(js & 1) * 512 + (size_t)l * 8;
    const unsigned short* wplo = Wlo + (size_t)(js >> 1) * 8192
                               + (size_t)(js & 1) * 512 + (size_t)l * 8;

    for (int s = 0; s < 8; ++s) {
        size_t fo = (size_t)s * 1024;
        bf16x8 bh = __builtin_bit_cast(bf16x8, *(const uint4*)(wphi + fo));
        bf16x8 bo = __builtin_bit_cast(bf16x8, *(const uint4*)(wplo + fo));
        const unsigned short* abase = (s < 4)
            ? (aggf + (size_t)s * 512 + (size_t)l * 8)
            : (hf + (size_t)(s - 4) * 512 + (size_t)l * 8);
        bf16x8 a0 = __builtin_bit_cast(bf16x8, *(const uint4*)(abase + (size_t)nb0 * 2048));
        bf16x8 a1 = __builtin_bit_cast(bf16x8, *(const uint4*)(abase + (size_t)(nb0 + 1) * 2048));
        acc0 = __builtin_amdgcn_mfma_f32_16x16x32_bf16(a0, bh, acc0, 0, 0, 0);
        acc0 = __builtin_amdgcn_mfma_f32_16x16x32_bf16(a0, bo, acc0, 0, 0, 0);
        acc1 = __builtin_amdgcn_mfma_f32_16x16x32_bf16(a1, bh, acc1, 0, 0, 0);
        acc1 = __builtin_amdgcn_mfma_f32_16x16x32_bf16(a1, bo, acc1, 0, 0, 0);
    }

    int g0 = do_pool ? batch[min(node0, n - 1)] : 0;
    int col = jbase + mr;
    float bias = bl[col];
    int q2 = (col >> 3) & 3;
    int e2 = col & 7;
    int so = col >> 5;

#pragma unroll
    for (int mi = 0; mi < 2; ++mi) {
        f32x4 a = mi ? acc1 : acc0;
#pragma unroll
        for (int r = 0; r < 4; ++r) {
            int node = node0 + mi * 16 + quad * 4 + r;
            if (node >= n) continue;
            float v = a[r] + bias;
            if (do_relu) v = fmaxf(v, 0.f);
            outf[(size_t)(node >> 4) * 2048 + (size_t)so * 512
                 + (size_t)(q2 * 16 + (node & 15)) * 8 + e2] = f2bf(v);
            if (do_out8) out8[(size_t)node * 128 + col] = f2fp8(v);
            if (do_pool) {
                int gi = batch[node] - g0;
                if (gi < 8) atomicAdd(&pool[gi][col], v);
                else atomicAdd(&gsum[batch[node] * 128 + col], v);
            }
        }
    }

    if (do_pool) {
        __syncthreads();
        for (int q = t; q < 1024; q += 256) {
            int s = q >> 7, c = q & 127;
            float v = pool[s][c];
            if (v != 0.f && g0 + s < 64)
                atomicAdd(&gsum[(g0 + s) * 128 + c], v);
        }
    }
}

// ---------------- final: mean-pool normalize + linear head -----------------
__global__ void k_final(const float* __restrict__ gsum, const int* __restrict__ batch,
                        const float* __restrict__ Wlin, const float* __restrict__ blin,
                        float* __restrict__ out, int n)
{
    int g = blockIdx.x;
    int o = threadIdx.x;
    int lo = 0, hi = n;
    while (lo < hi) { int m = (lo + hi) >> 1; if (batch[m] < g) lo = m + 1; else hi = m; }
    int lb = lo;
    hi = n;
    while (lo < hi) { int m = (lo + hi) >> 1; if (batch[m] < g + 1) lo = m + 1; else hi = m; }
    float cntf = (float)(lo - lb);
    float inv = 1.f / fmaxf(cntf, 1.f);
    float acc = 0.f;
    for (int k = 0; k < 128; ++k)
        acc += gsum[g * 128 + k] * Wlin[o * 128 + k];
    out[g * 64 + o] = acc * inv + blin[o];
}

extern "C" void kernel_launch(void* const* d_in, const int* in_sizes, int n_in,
                              void* d_out, int out_size, void* d_ws, size_t ws_size,
                              hipStream_t stream) {
    const float* x     = (const float*)d_in[0];
    const int*   ei    = (const int*)d_in[1];
    const int*   batch = (const int*)d_in[2];
    const float* W1l = (const float*)d_in[3];
    const float* b1l = (const float*)d_in[4];
    const float* W1r = (const float*)d_in[5];
    const float* W2l = (const float*)d_in[6];
    const float* b2l = (const float*)d_in[7];
    const float* W2r = (const float*)d_in[8];
    const float* W3l = (const float*)d_in[9];
    const float* b3l = (const float*)d_in[10];
    const float* W3r = (const float*)d_in[11];
    const float* Wlin = (const float*)d_in[12];
    const float* blin = (const float*)d_in[13];

    const int N = in_sizes[2];       // 50000
    const int E = in_sizes[1] / 2;   // 800000
    const int nb = (N + 127) >> 7;   // 391 buckets
    const int epb = (E + BINB - 1) / BINB;

    size_t off = 0;
    auto alloc = [&](size_t bytes) {
        void* p = (char*)d_ws + off;
        off += (bytes + 255) & ~(size_t)255;
        return p;
    };
    int* csr_start = (int*)alloc((size_t)(N + 1) * 4);
    int* cnt_mat   = (int*)alloc((size_t)nb * BINB * 4);
    int* rowloc    = (int*)alloc((size_t)nb * BINB * 4);
    int* btot      = (int*)alloc((size_t)NBMAX * 4);
    int* bbase     = (int*)alloc((size_t)NBMAX * 4);
    unsigned short* csr_src = (unsigned short*)alloc((size_t)E * 2);
    unsigned short* x_bf   = (unsigned short*)alloc((size_t)N * 128 * 2 + 65536);
    unsigned short* hA     = (unsigned short*)alloc((size_t)N * 128 * 2 + 65536);
    unsigned short* hB     = (unsigned short*)alloc((size_t)N * 128 * 2 + 65536);
    unsigned short* agg_bf = (unsigned short*)alloc((size_t)N * 128 * 2 + 65536);
    unsigned char*  h_f8   = (unsigned char*)alloc((size_t)N * 128);
    unsigned short* Whi = (unsigned short*)alloc(3 * 128 * 256 * 2);
    unsigned short* Wlo = (unsigned short*)alloc(3 * 128 * 256 * 2);
    float* gsum = (float*)alloc((size_t)64 * 128 * 4);
    (void)ws_size;

    unsigned* binned = (unsigned*)agg_bf;

    hipMemsetAsync(gsum, 0, (size_t)64 * 128 * 4, stream);

    // --- CSR build ---
    k_bincount<<<BINB, 256, 0, stream>>>(ei + E, cnt_mat, E, nb, epb);
    k_mrowscan<<<nb, 256, 0, stream>>>(cnt_mat, rowloc, btot);
    k_scan2b<<<1, 256, 0, stream>>>(btot, bbase, nb, csr_start + N);
    k_binscatter<<<BINB, 256, 0, stream>>>(ei, rowloc, bbase, binned, E, nb, epb);
    k_fillfine2<<<nb, 256, 0, stream>>>(binned, bbase, csr_start, csr_src, E, nb, N);

    // --- casts ---
    int n8 = N * 128 / 8;
    int nxblk = (n8 + 255) / 256;
    k_cast_all<<<nxblk + 3 * 128, 256, 0, stream>>>(
        x, x_bf, h_f8, n8, nxblk, W1l, W1r, W2l, W2r, W3l, W3r, Whi, Wlo);

    int agg_grid = (N + 3) / 4;
    int sage_grid = ((N + 31) / 32) * 2;   // pairs x j-halves = 3126

    // Layer 1
    k_agg<<<agg_grid, 256, 0, stream>>>(h_f8, csr_start, csr_src, agg_bf, N);
    k_sage<<<sage_grid, 256, 0, stream>>>(agg_bf, x_bf, Whi, Wlo, b1l,
                                          hA, h_f8, batch, gsum, N, 1, 1, 0);
    // Layer 2
    k_agg<<<agg_grid, 256, 0, stream>>>(h_f8, csr_start, csr_src, agg_bf, N);
    k_sage<<<sage_grid, 256, 0, stream>>>(agg_bf, hA, Whi + 32768, Wlo + 32768, b2l,
                                          hB, h_f8, batch, gsum, N, 1, 1, 0);
    // Layer 3 (no relu, pool fused)
    k_agg<<<agg_grid, 256, 0, stream>>>(h_f8, csr_start, csr_src, agg_bf, N);
    k_sage<<<sage_grid, 256, 0, stream>>>(agg_bf, hB, Whi + 65536, Wlo + 65536, b3l,
                                          hA, h_f8, batch, gsum, N, 0, 0, 1);

    // Head
    k_final<<<64, 64, 0, stream>>>(gsum, batch, Wlin, blin, (float*)d_out, N);
}

// Round 14
// 291.072 us; speedup vs baseline: 1.0422x; 1.0192x over previous
//
#include <hip/hip_runtime.h>

// HierarchicalGraphSAGE bf16-MFMA version, R14.
// N=50000, E=800000, D=128, OUT=64, G=64.
//
//  R14 vs R13: LAYER 3 COLLAPSED (no relu -> linear -> commutes with pool):
//   pooled3[g] = (sum_{edges->g} h2[src]) @ W3l^T/cnt
//              + (sum_{v in g} h2[v]) @ W3r^T/cnt + b3
//   - k_aggpool: layer-3 edge gather reduced straight into gsumE[64x128]
//     (LDS-merged per 16-node block), no aggf write, no sage3.
//   - k_poolh: fp8 column-sum pool of h2 -> gsumP[64x128].
//   - k_final: (gsumE@W3l + gsumP@W3r)/cnt + b3 -> @Wlin + blin, fp32.
//   - sage2 drops its bf16-fragment output (only consumer was sage3).
//  k_sage evidence trail: 4 structural variants all ~48-63us, MfmaUtil<5% --
//  per-wave latency floor; stop tuning it, remove one of its 3 dispatches.

typedef __bf16 bf16x8 __attribute__((ext_vector_type(8)));
typedef float f32x4 __attribute__((ext_vector_type(4)));
typedef float f32x2 __attribute__((ext_vector_type(2)));

#define BINB 160
#define NBMAX 512

static __device__ __forceinline__ float bf2f(unsigned short u) {
    union { unsigned u; float f; } c; c.u = (unsigned)u << 16; return c.f;
}
static __device__ __forceinline__ unsigned short f2bf(float f) {
    unsigned u = __builtin_bit_cast(unsigned, f);
    return (unsigned short)((u + 0x7fffu + ((u >> 16) & 1u)) >> 16);
}
static __device__ __forceinline__ uint2 pk8_fp8(const float* f) {
    int lo = 0, hi = 0;
    lo = __builtin_amdgcn_cvt_pk_fp8_f32(f[0], f[1], lo, false);
    lo = __builtin_amdgcn_cvt_pk_fp8_f32(f[2], f[3], lo, true);
    hi = __builtin_amdgcn_cvt_pk_fp8_f32(f[4], f[5], hi, false);
    hi = __builtin_amdgcn_cvt_pk_fp8_f32(f[6], f[7], hi, true);
    return make_uint2((unsigned)lo, (unsigned)hi);
}
static __device__ __forceinline__ unsigned char f2fp8(float v) {
    return (unsigned char)(__builtin_amdgcn_cvt_pk_fp8_f32(v, v, 0, false) & 0xff);
}

// ---------------- bucket counting sort ----------------
__global__ __launch_bounds__(256) void k_bincount(
    const int* __restrict__ dst, int* __restrict__ cnt_mat, int E, int nb, int epb)
{
    __shared__ int lc[NBMAX];
    for (int i = threadIdx.x; i < nb; i += 256) lc[i] = 0;
    __syncthreads();
    int b0 = blockIdx.x * epb;
    int b1 = min(b0 + epb, E);
    for (int i = b0 + threadIdx.x; i < b1; i += 256)
        atomicAdd(&lc[dst[i] >> 7], 1);
    __syncthreads();
    for (int i = threadIdx.x; i < nb; i += 256)
        cnt_mat[i * BINB + blockIdx.x] = lc[i];
}

__global__ __launch_bounds__(256) void k_mrowscan(
    const int* __restrict__ cnt_mat, int* __restrict__ rowloc, int* __restrict__ btot)
{
    __shared__ int s[256];
    int b = blockIdx.x;
    int t = threadIdx.x;
    int v = (t < BINB) ? cnt_mat[b * BINB + t] : 0;
    s[t] = v;
    __syncthreads();
#pragma unroll
    for (int off = 1; off < 256; off <<= 1) {
        int u = (t >= off) ? s[t - off] : 0;
        __syncthreads();
        s[t] += u;
        __syncthreads();
    }
    if (t < BINB) rowloc[b * BINB + t] = s[t] - v;
    if (t == 255) btot[b] = s[255];
}

__global__ __launch_bounds__(256) void k_scan2b(
    const int* __restrict__ btot, int* __restrict__ bbase, int nb, int* __restrict__ total_out)
{
    __shared__ int s[256];
    int t = threadIdx.x;
    int per = (nb + 255) / 256;
    int s0 = t * per, e0 = min(s0 + per, nb);
    int sum = 0;
    for (int i = s0; i < e0; ++i) sum += btot[i];
    s[t] = sum;
    __syncthreads();
#pragma unroll
    for (int off = 1; off < 256; off <<= 1) {
        int u = (t >= off) ? s[t - off] : 0;
        __syncthreads();
        s[t] += u;
        __syncthreads();
    }
    int run = s[t] - sum;
    for (int i = s0; i < e0; ++i) { bbase[i] = run; run += btot[i]; }
    if (t == 255) *total_out = s[255];
}

__global__ __launch_bounds__(256) void k_binscatter(
    const int* __restrict__ ei, const int* __restrict__ rowloc, const int* __restrict__ bbase,
    unsigned* __restrict__ binned, int E, int nb, int epb)
{
    __shared__ int lofs[NBMAX];
    __shared__ int lcnt[NBMAX];
    for (int i = threadIdx.x; i < nb; i += 256) {
        lofs[i] = rowloc[i * BINB + blockIdx.x] + bbase[i];
        lcnt[i] = 0;
    }
    __syncthreads();
    int b0 = blockIdx.x * epb;
    int b1 = min(b0 + epb, E);
    for (int i = b0 + threadIdx.x; i < b1; i += 256) {
        int s = ei[i];
        int d = ei[E + i];
        int b = d >> 7;
        int r = atomicAdd(&lcnt[b], 1);
        binned[lofs[b] + r] = (unsigned)s | ((unsigned)(d & 127) << 16);
    }
}

__global__ __launch_bounds__(256) void k_fillfine2(
    const unsigned* __restrict__ binned, const int* __restrict__ bbase,
    int* __restrict__ starts, unsigned short* __restrict__ csr_src,
    int E, int nb, int n)
{
    __shared__ int lc[128];
    __shared__ int lpos[128];
    int b = blockIdx.x;
    int t = threadIdx.x;
    int node0 = b << 7;
    int bs = bbase[b];
    int be = (b == nb - 1) ? E : bbase[b + 1];
    if (t < 128) lc[t] = 0;
    __syncthreads();
    for (int i = bs + t; i < be; i += 256)
        atomicAdd(&lc[(binned[i] >> 16) & 127], 1);
    __syncthreads();
    int v = (t < 128) ? lc[t] : 0;
    if (t < 128) lpos[t] = v;
    __syncthreads();
#pragma unroll
    for (int off = 1; off < 128; off <<= 1) {
        int u = (t >= off && t < 128) ? lpos[t - off] : 0;
        __syncthreads();
        if (t < 128) lpos[t] += u;
        __syncthreads();
    }
    int excl = (t < 128) ? (lpos[t] - v) : 0;
    __syncthreads();
    if (t < 128) {
        int node = node0 + t;
        if (node < n) starts[node] = bs + excl;
        lpos[t] = bs + excl;
    }
    if (b == nb - 1 && t == 0) starts[n] = E;
    __syncthreads();
    for (int i = bs + t; i < be; i += 256) {
        unsigned e = binned[i];
        int slot = atomicAdd(&lpos[(e >> 16) & 127], 1);
        csr_src[slot] = (unsigned short)(e & 0xffffu);
    }
}

// ---------------- casts: x -> bf16-fragments + fp8-rows; W1/W2 frag pack ---
__global__ __launch_bounds__(256) void k_cast_all(
    const float* __restrict__ x, unsigned short* __restrict__ xb,
    unsigned char* __restrict__ x8, int n8, int nxblk,
    const float* __restrict__ W1l, const float* __restrict__ W1r,
    const float* __restrict__ W2l, const float* __restrict__ W2r,
    unsigned short* __restrict__ Whi, unsigned short* __restrict__ Wlo)
{
    int bid = blockIdx.x;
    if (bid < nxblk) {
        int i = bid * 256 + threadIdx.x;
        if (i >= n8) return;
        float f[8];
        *(float4*)(f + 0) = *(const float4*)(x + (size_t)i * 8);
        *(float4*)(f + 4) = *(const float4*)(x + (size_t)i * 8 + 4);
        ushort4 oa, ob;
        oa.x = f2bf(f[0]); oa.y = f2bf(f[1]); oa.z = f2bf(f[2]); oa.w = f2bf(f[3]);
        ob.x = f2bf(f[4]); ob.y = f2bf(f[5]); ob.z = f2bf(f[6]); ob.w = f2bf(f[7]);
        int node = i >> 4, c = i & 15;
        size_t dst = (size_t)(node >> 4) * 2048 + (size_t)(c >> 2) * 512
                   + (size_t)((c & 3) * 16 + (node & 15)) * 8;
        *(ushort4*)(xb + dst) = oa;
        *(ushort4*)(xb + dst + 4) = ob;
        *(uint2*)(x8 + (size_t)i * 8) = pk8_fp8(f);
    } else {
        int wb = bid - nxblk;          // 0..255 (2 layers)
        int layer = wb >> 7;
        int j = wb & 127;
        int k = threadIdx.x;
        const float* Wl = (layer == 0) ? W1l : W2l;
        const float* Wr = (layer == 0) ? W1r : W2r;
        float w = (k < 128) ? Wl[j * 128 + k] : Wr[j * 128 + k - 128];
        unsigned short hi = f2bf(w);
        float lo = w - bf2f(hi);
        int wv = j >> 5, jj = (j >> 4) & 1, mr = j & 15;
        int s = k >> 5, quad = (k >> 3) & 3, e = k & 7;
        int lane = quad * 16 + mr;
        size_t o = (size_t)layer * 32768
                 + ((size_t)(((wv * 8 + s) * 2 + jj)) * 64 + lane) * 8 + e;
        Whi[o] = hi;
        Wlo[o] = f2bf(lo);
    }
}

// ---------------- gather macro body (shared by k_agg / k_aggpool) ----------
#define GATHER_NODE(node)                                               \
    float a0 = 0.f, a1 = 0.f, a2 = 0.f, a3 = 0.f,                       \
          a4 = 0.f, a5 = 0.f, a6 = 0.f, a7 = 0.f;                       \
    {                                                                   \
        int s = starts[node], e = starts[node + 1];                     \
        for (int base = s; base < e; base += 64) {                      \
            int cnt = min(64, e - base);                                \
            int idx = (base + lane < e) ? (int)csr[base + lane] : 0;    \
            int j = 0;                                                  \
            for (; j + 8 <= cnt; j += 8) {                              \
                int s0 = __shfl(idx, j + eg);                           \
                int s1 = __shfl(idx, j + 4 + eg);                       \
                uint2 v0 = *(const uint2*)(hrow + (size_t)s0 * 128);    \
                uint2 v1 = *(const uint2*)(hrow + (size_t)s1 * 128);    \
                ACC8(v0);                                               \
                ACC8(v1);                                               \
            }                                                           \
            for (; j + 4 <= cnt; j += 4) {                              \
                int s0 = __shfl(idx, j + eg);                           \
                uint2 v0 = *(const uint2*)(hrow + (size_t)s0 * 128);    \
                ACC8(v0);                                               \
            }                                                           \
            if (j < cnt) {                                              \
                int k = j + eg;                                         \
                int sm = __shfl(idx, (k < cnt) ? k : (cnt - 1));        \
                uint2 v = *(const uint2*)(hrow + (size_t)sm * 128);     \
                if (k >= cnt) v = make_uint2(0u, 0u);                   \
                ACC8(v);                                                \
            }                                                           \
        }                                                               \
    }                                                                   \
    a0 += __shfl_xor(a0, 16); a0 += __shfl_xor(a0, 32);                 \
    a1 += __shfl_xor(a1, 16); a1 += __shfl_xor(a1, 32);                 \
    a2 += __shfl_xor(a2, 16); a2 += __shfl_xor(a2, 32);                 \
    a3 += __shfl_xor(a3, 16); a3 += __shfl_xor(a3, 32);                 \
    a4 += __shfl_xor(a4, 16); a4 += __shfl_xor(a4, 32);                 \
    a5 += __shfl_xor(a5, 16); a5 += __shfl_xor(a5, 32);                 \
    a6 += __shfl_xor(a6, 16); a6 += __shfl_xor(a6, 32);                 \
    a7 += __shfl_xor(a7, 16); a7 += __shfl_xor(a7, 32);

#define ACC8(v)                                                         \
    do {                                                                \
        f32x2 p0 = __builtin_amdgcn_cvt_pk_f32_fp8((v).x, false);       \
        f32x2 p1 = __builtin_amdgcn_cvt_pk_f32_fp8((v).x, true);        \
        f32x2 p2 = __builtin_amdgcn_cvt_pk_f32_fp8((v).y, false);       \
        f32x2 p3 = __builtin_amdgcn_cvt_pk_f32_fp8((v).y, true);        \
        a0 += p0.x; a1 += p0.y; a2 += p1.x; a3 += p1.y;                 \
        a4 += p2.x; a5 += p2.y; a6 += p3.x; a7 += p3.y;                 \
    } while (0)

// ---------------- aggregate: fp8-row gather -> fragment-packed bf16 agg ----
__global__ __launch_bounds__(256) void k_agg(
    const unsigned char* __restrict__ h8, const int* __restrict__ starts,
    const unsigned short* __restrict__ csr, unsigned short* __restrict__ aggf, int n)
{
    int node = blockIdx.x * 4 + (threadIdx.x >> 6);
    int lane = threadIdx.x & 63;
    if (node >= n) return;
    int eg = lane >> 4;
    int fb = lane & 15;
    const unsigned char* hrow = h8 + fb * 8;

    GATHER_NODE(node)

    unsigned u0 = (unsigned)f2bf(a0) | ((unsigned)f2bf(a1) << 16);
    unsigned u1 = (unsigned)f2bf(a2) | ((unsigned)f2bf(a3) << 16);
    unsigned u2 = (unsigned)f2bf(a4) | ((unsigned)f2bf(a5) << 16);
    unsigned u3 = (unsigned)f2bf(a6) | ((unsigned)f2bf(a7) << 16);
    if (eg == 0) {
        size_t dst = (size_t)(node >> 4) * 2048 + (size_t)(fb >> 2) * 512
                   + (size_t)((fb & 3) * 16 + (node & 15)) * 8;
        *(uint4*)(aggf + dst) = make_uint4(u0, u1, u2, u3);
    }
}

// ---------------- layer-3 collapsed: edge gather -> per-graph sum ----------
// Block = 16 nodes (4 waves x 4 nodes). Per-node aggregate reduced into a
// 4-slot LDS graph buffer (16 consecutive sorted nodes span <=2 graphs in
// practice), one block-level flush of ~128-256 atomics.
__global__ __launch_bounds__(256) void k_aggpool(
    const unsigned char* __restrict__ h8, const int* __restrict__ starts,
    const unsigned short* __restrict__ csr, const int* __restrict__ batch,
    float* __restrict__ gsumE, int n)
{
    __shared__ float gbuf[4][128];
    int t = threadIdx.x;
    int node00 = blockIdx.x * 16;
    if (node00 >= n) return;
    for (int q = t; q < 512; q += 256) gbuf[q >> 7][q & 127] = 0.f;
    __syncthreads();
    int g0 = batch[node00];
    int wv = t >> 6;
    int lane = t & 63;
    int eg = lane >> 4;
    int fb = lane & 15;
    const unsigned char* hrow = h8 + fb * 8;

    for (int i = 0; i < 4; ++i) {
        int node = node00 + wv * 4 + i;
        if (node >= n) break;

        GATHER_NODE(node)

        if (eg == 0) {
            int g = batch[node];
            int gi = g - g0;
            if (gi < 4) {
                float* d = &gbuf[gi][fb * 8];
                atomicAdd(d + 0, a0); atomicAdd(d + 1, a1);
                atomicAdd(d + 2, a2); atomicAdd(d + 3, a3);
                atomicAdd(d + 4, a4); atomicAdd(d + 5, a5);
                atomicAdd(d + 6, a6); atomicAdd(d + 7, a7);
            } else {
                float* d = &gsumE[(size_t)g * 128 + fb * 8];
                atomicAdd(d + 0, a0); atomicAdd(d + 1, a1);
                atomicAdd(d + 2, a2); atomicAdd(d + 3, a3);
                atomicAdd(d + 4, a4); atomicAdd(d + 5, a5);
                atomicAdd(d + 6, a6); atomicAdd(d + 7, a7);
            }
        }
    }
    __syncthreads();
    for (int q = t; q < 512; q += 256) {
        int sl = q >> 7, c = q & 127;
        float v = gbuf[sl][c];
        if (v != 0.f && g0 + sl < 64)
            atomicAdd(&gsumE[(size_t)(g0 + sl) * 128 + c], v);
    }
}

// ---------------- SAGE layer GEMM: 32 nodes x 16 j per wave ----------------
__global__ __launch_bounds__(256) void k_sage(
    const unsigned short* __restrict__ aggf, const unsigned short* __restrict__ hf,
    const unsigned short* __restrict__ Whi, const unsigned short* __restrict__ Wlo,
    const float* __restrict__ bl, unsigned short* __restrict__ outf,
    unsigned char* __restrict__ out8, int n, int do_relu, int do_outf)
{
    int bid = blockIdx.x;
    int pair = bid >> 1;
    int jh = bid & 1;
    int t = threadIdx.x;
    int wv = t >> 6;
    int l = t & 63;
    int quad = l >> 4;
    int mr = l & 15;
    int js = jh * 4 + wv;
    int jbase = js * 16;
    int nb0 = pair * 2;
    int node0 = pair * 32;

    f32x4 acc0 = (f32x4){0.f, 0.f, 0.f, 0.f};
    f32x4 acc1 = (f32x4){0.f, 0.f, 0.f, 0.f};

    const unsigned short* wphi = Whi + (size_t)(js >> 1) * 8192
                               + (size_t)(js & 1) * 512 + (size_t)l * 8;
    const unsigned short* wplo = Wlo + (size_t)(js >> 1) * 8192
                               + (size_t)(js & 1) * 512 + (size_t)l * 8;

    for (int s = 0; s < 8; ++s) {
        size_t fo = (size_t)s * 1024;
        bf16x8 bh = __builtin_bit_cast(bf16x8, *(const uint4*)(wphi + fo));
        bf16x8 bo = __builtin_bit_cast(bf16x8, *(const uint4*)(wplo + fo));
        const unsigned short* abase = (s < 4)
            ? (aggf + (size_t)s * 512 + (size_t)l * 8)
            : (hf + (size_t)(s - 4) * 512 + (size_t)l * 8);
        bf16x8 a0 = __builtin_bit_cast(bf16x8, *(const uint4*)(abase + (size_t)nb0 * 2048));
        bf16x8 a1 = __builtin_bit_cast(bf16x8, *(const uint4*)(abase + (size_t)(nb0 + 1) * 2048));
        acc0 = __builtin_amdgcn_mfma_f32_16x16x32_bf16(a0, bh, acc0, 0, 0, 0);
        acc0 = __builtin_amdgcn_mfma_f32_16x16x32_bf16(a0, bo, acc0, 0, 0, 0);
        acc1 = __builtin_amdgcn_mfma_f32_16x16x32_bf16(a1, bh, acc1, 0, 0, 0);
        acc1 = __builtin_amdgcn_mfma_f32_16x16x32_bf16(a1, bo, acc1, 0, 0, 0);
    }

    int col = jbase + mr;
    float bias = bl[col];
    int q2 = (col >> 3) & 3;
    int e2 = col & 7;
    int so = col >> 5;

#pragma unroll
    for (int mi = 0; mi < 2; ++mi) {
        f32x4 a = mi ? acc1 : acc0;
#pragma unroll
        for (int r = 0; r < 4; ++r) {
            int node = node0 + mi * 16 + quad * 4 + r;
            if (node >= n) continue;
            float v = a[r] + bias;
            if (do_relu) v = fmaxf(v, 0.f);
            if (do_outf)
                outf[(size_t)(node >> 4) * 2048 + (size_t)so * 512
                     + (size_t)(q2 * 16 + (node & 15)) * 8 + e2] = f2bf(v);
            out8[(size_t)node * 128 + col] = f2fp8(v);
        }
    }
}

// ---------------- pool of h2 (fp8 rows) -> per-graph sum -------------------
__global__ __launch_bounds__(256) void k_poolh(
    const unsigned char* __restrict__ h8, const int* __restrict__ batch,
    float* __restrict__ gsumP, int n)
{
    int wave = (blockIdx.x * 256 + threadIdx.x) >> 6;
    int lane = threadIdx.x & 63;
    int r0 = wave * 16;
    if (r0 >= n) return;
    int r1 = min(r0 + 16, n);
    int cur = batch[r0];
    float ax = 0.f, ay = 0.f;
    for (int i = r0; i < r1; ++i) {
        int g = batch[i];
        uchar2 v = *(const uchar2*)(h8 + (size_t)i * 128 + lane * 2);
        if (g != cur) {
            atomicAdd(&gsumP[cur * 128 + lane * 2], ax);
            atomicAdd(&gsumP[cur * 128 + lane * 2 + 1], ay);
            ax = 0.f; ay = 0.f; cur = g;
        }
        unsigned pk = (unsigned)v.x | ((unsigned)v.y << 8);
        f32x2 p = __builtin_amdgcn_cvt_pk_f32_fp8((int)pk, false);
        ax += p.x;
        ay += p.y;
    }
    atomicAdd(&gsumP[cur * 128 + lane * 2], ax);
    atomicAdd(&gsumP[cur * 128 + lane * 2 + 1], ay);
}

// ---------------- final: collapsed layer 3 + mean + head, fp32 -------------
__global__ __launch_bounds__(128) void k_final(
    const float* __restrict__ gsumE, const float* __restrict__ gsumP,
    const int* __restrict__ batch,
    const float* __restrict__ W3l, const float* __restrict__ b3,
    const float* __restrict__ W3r,
    const float* __restrict__ Wlin, const float* __restrict__ blin,
    float* __restrict__ out, int n)
{
    __shared__ float tmp[128];
    int g = blockIdx.x;   // 64
    int t = threadIdx.x;  // 128
    // count via binary search on sorted batch
    int lo = 0, hi = n;
    while (lo < hi) { int m = (lo + hi) >> 1; if (batch[m] < g) lo = m + 1; else hi = m; }
    int lb = lo;
    hi = n;
    while (lo < hi) { int m = (lo + hi) >> 1; if (batch[m] < g + 1) lo = m + 1; else hi = m; }
    int cnt = lo - lb;
    float inv = (cnt > 0) ? 1.f / (float)cnt : 0.f;

    float acc = 0.f;
    for (int k = 0; k < 128; ++k)
        acc += gsumE[g * 128 + k] * W3l[t * 128 + k]
             + gsumP[g * 128 + k] * W3r[t * 128 + k];
    tmp[t] = acc * inv + ((cnt > 0) ? b3[t] : 0.f);
    __syncthreads();

    if (t < 64) {
        float o = 0.f;
        for (int k = 0; k < 128; ++k)
            o += tmp[k] * Wlin[t * 128 + k];
        out[g * 64 + t] = o + blin[t];
    }
}

extern "C" void kernel_launch(void* const* d_in, const int* in_sizes, int n_in,
                              void* d_out, int out_size, void* d_ws, size_t ws_size,
                              hipStream_t stream) {
    const float* x     = (const float*)d_in[0];
    const int*   ei    = (const int*)d_in[1];
    const int*   batch = (const int*)d_in[2];
    const float* W1l = (const float*)d_in[3];
    const float* b1l = (const float*)d_in[4];
    const float* W1r = (const float*)d_in[5];
    const float* W2l = (const float*)d_in[6];
    const float* b2l = (const float*)d_in[7];
    const float* W2r = (const float*)d_in[8];
    const float* W3l = (const float*)d_in[9];
    const float* b3l = (const float*)d_in[10];
    const float* W3r = (const float*)d_in[11];
    const float* Wlin = (const float*)d_in[12];
    const float* blin = (const float*)d_in[13];

    const int N = in_sizes[2];       // 50000
    const int E = in_sizes[1] / 2;   // 800000
    const int nb = (N + 127) >> 7;   // 391 buckets
    const int epb = (E + BINB - 1) / BINB;

    size_t off = 0;
    auto alloc = [&](size_t bytes) {
        void* p = (char*)d_ws + off;
        off += (bytes + 255) & ~(size_t)255;
        return p;
    };
    int* csr_start = (int*)alloc((size_t)(N + 1) * 4);
    int* cnt_mat   = (int*)alloc((size_t)nb * BINB * 4);
    int* rowloc    = (int*)alloc((size_t)nb * BINB * 4);
    int* btot      = (int*)alloc((size_t)NBMAX * 4);
    int* bbase     = (int*)alloc((size_t)NBMAX * 4);
    unsigned short* csr_src = (unsigned short*)alloc((size_t)E * 2);
    unsigned short* x_bf   = (unsigned short*)alloc((size_t)N * 128 * 2 + 65536);
    unsigned short* hA     = (unsigned short*)alloc((size_t)N * 128 * 2 + 65536);
    unsigned short* agg_bf = (unsigned short*)alloc((size_t)N * 128 * 2 + 65536);
    unsigned char*  h_f8   = (unsigned char*)alloc((size_t)N * 128);
    unsigned short* Whi = (unsigned short*)alloc(2 * 128 * 256 * 2);
    unsigned short* Wlo = (unsigned short*)alloc(2 * 128 * 256 * 2);
    float* gsumE = (float*)alloc((size_t)64 * 128 * 4);   // adjacent to gsumP
    float* gsumP = (float*)alloc((size_t)64 * 128 * 4);
    (void)ws_size;

    unsigned* binned = (unsigned*)agg_bf;

    hipMemsetAsync(gsumE, 0, (size_t)2 * 64 * 128 * 4, stream);  // E+P adjacent

    // --- CSR build ---
    k_bincount<<<BINB, 256, 0, stream>>>(ei + E, cnt_mat, E, nb, epb);
    k_mrowscan<<<nb, 256, 0, stream>>>(cnt_mat, rowloc, btot);
    k_scan2b<<<1, 256, 0, stream>>>(btot, bbase, nb, csr_start + N);
    k_binscatter<<<BINB, 256, 0, stream>>>(ei, rowloc, bbase, binned, E, nb, epb);
    k_fillfine2<<<nb, 256, 0, stream>>>(binned, bbase, csr_start, csr_src, E, nb, N);

    // --- casts ---
    int n8 = N * 128 / 8;
    int nxblk = (n8 + 255) / 256;
    k_cast_all<<<nxblk + 2 * 128, 256, 0, stream>>>(
        x, x_bf, h_f8, n8, nxblk, W1l, W1r, W2l, W2r, Whi, Wlo);

    int agg_grid = (N + 3) / 4;
    int sage_grid = ((N + 31) / 32) * 2;
    int pool_grid = (((N + 15) / 16) + 3) / 4;

    // Layer 1: gather fp8(x) -> agg frags; GEMM -> h1 frags (relu) + fp8 rows
    k_agg<<<agg_grid, 256, 0, stream>>>(h_f8, csr_start, csr_src, agg_bf, N);
    k_sage<<<sage_grid, 256, 0, stream>>>(agg_bf, x_bf, Whi, Wlo, b1l,
                                          hA, h_f8, N, 1, 1);
    // Layer 2: gather fp8(h1) -> agg frags; GEMM -> fp8 rows only (h2)
    k_agg<<<agg_grid, 256, 0, stream>>>(h_f8, csr_start, csr_src, agg_bf, N);
    k_sage<<<sage_grid, 256, 0, stream>>>(agg_bf, hA, Whi + 32768, Wlo + 32768, b2l,
                                          hA, h_f8, N, 1, 0);
    // Layer 3 collapsed: edge-sum(h2) per graph + node-sum(h2) per graph
    k_aggpool<<<(N + 15) / 16, 256, 0, stream>>>(h_f8, csr_start, csr_src, batch, gsumE, N);
    k_poolh<<<pool_grid, 256, 0, stream>>>(h_f8, batch, gsumP, N);

    // Head: (gsumE@W3l + gsumP@W3r)/cnt + b3 -> @Wlin + blin
    k_final<<<64, 128, 0, stream>>>(gsumE, gsumP, batch, W3l, b3l, W3r,
                                    Wlin, blin, (float*)d_out, N);
}